// Round 8
// baseline (7030.995 us; speedup 1.0000x reference)
//
#include <hip/hip_runtime.h>
#include <cmath>

#define B_ 64
#define T_ 512
#define E_ 512
#define H_ 1024
#define O_ 512
#define BH (B_ * H_)
#define HSTRIDE 1160  // LDS row stride (elems); 16B aligned, conflict-benign

typedef unsigned short ushort_t;
typedef __bf16 bf16x8 __attribute__((ext_vector_type(8)));
typedef float f32x4 __attribute__((ext_vector_type(4)));

__device__ __forceinline__ ushort_t f2bf(float f) {
    union { float f; unsigned int u; } x; x.f = f;
    unsigned int r = x.u + 0x7fffu + ((x.u >> 16) & 1u);
    return (ushort_t)(r >> 16);
}
__device__ __forceinline__ float bf2f(ushort_t u) {
    union { unsigned int u; float f; } x; x.u = ((unsigned int)u) << 16;
    return x.f;
}
__device__ __forceinline__ uint4 pack8bf(float4 v0, float4 v1) {
    uint4 pk;
    pk.x = (unsigned)f2bf(v0.x) | ((unsigned)f2bf(v0.y) << 16);
    pk.y = (unsigned)f2bf(v0.z) | ((unsigned)f2bf(v0.w) << 16);
    pk.z = (unsigned)f2bf(v1.x) | ((unsigned)f2bf(v1.y) << 16);
    pk.w = (unsigned)f2bf(v1.z) | ((unsigned)f2bf(v1.w) << 16);
    return pk;
}
__device__ __forceinline__ bf16x8 pack8(const float* src) {
    float4 v0 = *(const float4*)src;
    float4 v1 = *(const float4*)(src + 4);
    union { uint4 u; bf16x8 b; } c;
    c.u = pack8bf(v0, v1);
    return c.b;
}

// ---------------------------------------------------------------- prep ------
__global__ void prep_kernel(const float* __restrict__ h0, ushort_t* __restrict__ hinit,
                            int* __restrict__ bar) {
    int i = blockIdx.x * blockDim.x + threadIdx.x;
    if (i < 16384) bar[i] = 0;  // flags: 2 layers x 4 groups x 64 flags x 32-int stride
    if (i < 2 * BH) hinit[i] = f2bf(h0[i]);
}

// ------------------------------------------------ big GEMM: C = A*W^T + b ---
// MODE 0: A fp32 (emb, (B,T,E), row r=t*64+b -> emb row (b,t)), out bf16 direct rows
// MODE 2: A bf16 direct rows, out fp32 remapped row r=t*64+b -> out row (b,t)
template <int MODE>
__launch_bounds__(256)
__global__ void gemm_bt(const void* __restrict__ Ap, const float* __restrict__ Wp,
                        const float* __restrict__ bias, void* __restrict__ outp,
                        int N, int K) {
    __shared__ __align__(16) ushort_t As[128 * 72];
    __shared__ __align__(16) ushort_t Bs[128 * 72];
    const int tid = threadIdx.x;
    const int lane = tid & 63;
    const int w = tid >> 6;
    const int wm = (w >> 1) * 64;
    const int wn = (w & 1) * 64;
    const int q = lane >> 4;
    const int l16 = lane & 15;
    const int m0 = blockIdx.y * 128;
    const int n0 = blockIdx.x * 128;

    const float*    Af = (const float*)Ap;
    const ushort_t* Ab = (const ushort_t*)Ap;

    f32x4 zero = {0.f, 0.f, 0.f, 0.f};
    f32x4 acc[4][4];
#pragma unroll
    for (int i = 0; i < 4; i++)
#pragma unroll
        for (int j = 0; j < 4; j++) acc[i][j] = zero;

    for (int k0 = 0; k0 < K; k0 += 64) {
#pragma unroll
        for (int it = 0; it < 4; it++) {
            int task = tid + it * 256;
            int row = task >> 3, seg = task & 7;
            if (MODE == 0) {
                int Ra = m0 + row;
                const float* src = Af + (size_t)((Ra & 63) * T_ + (Ra >> 6)) * K + k0 + seg * 8;
                float4 v0 = *(const float4*)src;
                float4 v1 = *(const float4*)(src + 4);
                *(uint4*)&As[row * 72 + seg * 8] = pack8bf(v0, v1);
            } else {
                const ushort_t* src = Ab + (size_t)(m0 + row) * K + k0 + seg * 8;
                *(uint4*)&As[row * 72 + seg * 8] = *(const uint4*)src;
            }
            const float* wsrc = Wp + (size_t)(n0 + row) * K + k0 + seg * 8;
            float4 w0 = *(const float4*)wsrc;
            float4 w1 = *(const float4*)(wsrc + 4);
            *(uint4*)&Bs[row * 72 + seg * 8] = pack8bf(w0, w1);
        }
        __syncthreads();
#pragma unroll
        for (int ks = 0; ks < 64; ks += 32) {
            bf16x8 af[4], bfr[4];
#pragma unroll
            for (int i = 0; i < 4; i++)
                af[i] = *(const bf16x8*)&As[(wm + i * 16 + l16) * 72 + ks + q * 8];
#pragma unroll
            for (int j = 0; j < 4; j++)
                bfr[j] = *(const bf16x8*)&Bs[(wn + j * 16 + l16) * 72 + ks + q * 8];
#pragma unroll
            for (int i = 0; i < 4; i++)
#pragma unroll
                for (int j = 0; j < 4; j++)
                    acc[i][j] = __builtin_amdgcn_mfma_f32_16x16x32_bf16(af[i], bfr[j], acc[i][j], 0, 0, 0);
        }
        __syncthreads();
    }

#pragma unroll
    for (int j = 0; j < 4; j++) {
        int C = n0 + wn + j * 16 + l16;
        float bv = bias[C];
#pragma unroll
        for (int i = 0; i < 4; i++) {
#pragma unroll
            for (int r = 0; r < 4; r++) {
                int R = m0 + wm + i * 16 + q * 4 + r;
                float v = acc[i][j][r] + bv;
                if (MODE == 2) {
                    ((float*)outp)[(size_t)((R & 63) * T_ + (R >> 6)) * N + C] = v;
                } else {
                    ((ushort_t*)outp)[(size_t)R * N + C] = f2bf(v);
                }
            }
        }
    }
}

// ------------------- two-pass recurrence, per-wave col tiles ----------------
// 64 blocks x 256 threads per pass. Block (gb, cb): batch rows [16gb,+16),
// cols [64cb,+64). Wave w owns cols [64cb+16w,+16), FULL K=1024 (32 MFMAs,
// B-frags in registers) -> no cross-wave reduce, no Rs.
// Barrier: per-WAVE flags (64/group). Wave drains own stores (vmcnt0) then
// publishes flag = r+1. Consumers poll all 64 flags (lane i -> flag i, ballot).
// The poll is also the LDS WAR guard: a wave's next-round LDS staging write is
// gated on every co-block wave's flag, which follows that wave's ds_reads.
// LAYER 0: h[r] = tanh(h[r-1]·Wa^T + x[r] + ba); x read 4x ushort in staging,
//          h[r] overwrites x[r] in xall (=xp).
// LAYER 1: h[r] = tanh(xsrc[r]·Wa^T + h[r-1]·Wb^T + ba+bb); x-part MFMA'd
//          pre-poll from direct-global A-frags (xsrc materialized, plain loads).
template <int LAYER>
__launch_bounds__(256, 1)
__global__ void rnn_wave(ushort_t* __restrict__ xall,
                         const ushort_t* __restrict__ xsrc,
                         const ushort_t* __restrict__ hin,
                         const float* __restrict__ Wa, const float* __restrict__ Wb,
                         const float* __restrict__ ba, const float* __restrict__ bb,
                         int* __restrict__ bar) {
    __shared__ __align__(16) ushort_t Hs[16 * HSTRIDE];  // recurrent-state tile

    const int tid = threadIdx.x;
    const int lane = tid & 63;
    const int w = tid >> 6;
    const int q = lane >> 4;
    const int l16 = lane & 15;
    const int gb = blockIdx.x >> 4;   // 4 batch groups
    const int cb = blockIdx.x & 15;   // 16 col blocks of 64
    const int b0 = gb * 16;
    const int c = cb * 64 + w * 16 + l16;   // this lane's output column
    int* flags = bar + (LAYER * 4 + gb) * 2048;
    int* pollp = flags + (lane << 5);             // lane i polls flag i
    int* myflag = flags + ((cb * 4 + w) << 5);    // this wave's flag

    // ---- register B-fragments (own col, full K)
    bf16x8 wA[32], wB[32];
#pragma unroll
    for (int kk = 0; kk < 32; kk++) {
        size_t off = (size_t)c * H_ + kk * 32 + q * 8;
        wA[kk] = pack8(Wa + off);
        if (LAYER == 1) wB[kk] = pack8(Wb + off);
    }
    float bv = ba[c];
    if (LAYER == 1) bv += bb[c];

    const int rbase2 = (tid >> 7) * 2;  // 0 or 2
    const int seg = tid & 127;          // 16B segment in row

    for (int r = 0; r < 512; r++) {
        f32x4 acc = {0.f, 0.f, 0.f, 0.f};

        if (LAYER == 1) {
            // ---- x-part pre-poll: direct-global A-frags from xsrc[r] (plain,
            //      cached; materialized by previous dispatch). Overlaps wait.
            const ushort_t* ax = xsrc + (size_t)r * BH + (size_t)(b0 + l16) * H_ + q * 8;
#pragma unroll
            for (int kk = 0; kk < 32; kk++) {
                bf16x8 a = *(const bf16x8*)(ax + kk * 32);
                acc = __builtin_amdgcn_mfma_f32_16x16x32_bf16(a, wA[kk], acc, 0, 0, 0);
            }
        }

        // ---- wait: all 64 wave-tiles of this group published round r
        if (r > 0) {
            while (true) {
                int v = __hip_atomic_load(pollp, __ATOMIC_RELAXED, __HIP_MEMORY_SCOPE_SYSTEM);
                if (__ballot(v >= r) == ~0ull) break;
            }
        }

        // ---- stage recurrent tile (sc0sc1) [+ 4 x-ushorts for LAYER 0]
        const ushort_t* hsrc = (r == 0) ? hin : (xall + (size_t)(r - 1) * BH);
        const ushort_t* c0 = hsrc + (size_t)(b0 + rbase2) * H_ + seg * 8;
        const ushort_t* c1 = c0 + 4 * H_;
        const ushort_t* c2 = c0 + 8 * H_;
        const ushort_t* c3 = c0 + 12 * H_;
        ushort_t* xrow0 = xall + (size_t)r * BH + (size_t)(b0 + q * 4) * H_ + c;
        ushort_t* xrow2 = xrow0 + 2 * H_;
        uint4 e0, e1, e2, e3, e4, e5, e6, e7;
        unsigned x0 = 0, x1 = 0, x2 = 0, x3 = 0;
        if (LAYER == 0) {
            asm volatile(
                "global_load_dwordx4 %0, %12, off sc0 sc1\n\t"
                "global_load_dwordx4 %1, %12, off offset:2048 sc0 sc1\n\t"
                "global_load_dwordx4 %2, %13, off sc0 sc1\n\t"
                "global_load_dwordx4 %3, %13, off offset:2048 sc0 sc1\n\t"
                "global_load_dwordx4 %4, %14, off sc0 sc1\n\t"
                "global_load_dwordx4 %5, %14, off offset:2048 sc0 sc1\n\t"
                "global_load_dwordx4 %6, %15, off sc0 sc1\n\t"
                "global_load_dwordx4 %7, %15, off offset:2048 sc0 sc1\n\t"
                "global_load_ushort %8, %16, off sc0 sc1\n\t"
                "global_load_ushort %9, %16, off offset:2048 sc0 sc1\n\t"
                "global_load_ushort %10, %17, off sc0 sc1\n\t"
                "global_load_ushort %11, %17, off offset:2048 sc0 sc1\n\t"
                "s_waitcnt vmcnt(0)"
                : "=&v"(e0), "=&v"(e1), "=&v"(e2), "=&v"(e3),
                  "=&v"(e4), "=&v"(e5), "=&v"(e6), "=&v"(e7),
                  "=&v"(x0), "=&v"(x1), "=&v"(x2), "=&v"(x3)
                : "v"(c0), "v"(c1), "v"(c2), "v"(c3), "v"(xrow0), "v"(xrow2)
                : "memory");
        } else {
            asm volatile(
                "global_load_dwordx4 %0, %8, off sc0 sc1\n\t"
                "global_load_dwordx4 %1, %8, off offset:2048 sc0 sc1\n\t"
                "global_load_dwordx4 %2, %9, off sc0 sc1\n\t"
                "global_load_dwordx4 %3, %9, off offset:2048 sc0 sc1\n\t"
                "global_load_dwordx4 %4, %10, off sc0 sc1\n\t"
                "global_load_dwordx4 %5, %10, off offset:2048 sc0 sc1\n\t"
                "global_load_dwordx4 %6, %11, off sc0 sc1\n\t"
                "global_load_dwordx4 %7, %11, off offset:2048 sc0 sc1\n\t"
                "s_waitcnt vmcnt(0)"
                : "=&v"(e0), "=&v"(e1), "=&v"(e2), "=&v"(e3),
                  "=&v"(e4), "=&v"(e5), "=&v"(e6), "=&v"(e7)
                : "v"(c0), "v"(c1), "v"(c2), "v"(c3)
                : "memory");
        }
        *(uint4*)&Hs[(rbase2 + 0) * HSTRIDE + seg * 8] = e0;
        *(uint4*)&Hs[(rbase2 + 1) * HSTRIDE + seg * 8] = e1;
        *(uint4*)&Hs[(rbase2 + 4) * HSTRIDE + seg * 8] = e2;
        *(uint4*)&Hs[(rbase2 + 5) * HSTRIDE + seg * 8] = e3;
        *(uint4*)&Hs[(rbase2 + 8) * HSTRIDE + seg * 8] = e4;
        *(uint4*)&Hs[(rbase2 + 9) * HSTRIDE + seg * 8] = e5;
        *(uint4*)&Hs[(rbase2 + 12) * HSTRIDE + seg * 8] = e6;
        *(uint4*)&Hs[(rbase2 + 13) * HSTRIDE + seg * 8] = e7;
        __syncthreads();   // staging visible to all waves (single barrier/round)

        // ---- h-part: wave's 16 cols, full K (32 MFMAs, acc continues)
        const bf16x8* wH = (LAYER == 1) ? wB : wA;
#pragma unroll
        for (int kk = 0; kk < 32; kk++) {
            bf16x8 a = *(const bf16x8*)&Hs[l16 * HSTRIDE + kk * 32 + q * 8];
            acc = __builtin_amdgcn_mfma_f32_16x16x32_bf16(a, wH[kk], acc, 0, 0, 0);
        }

        // ---- epilogue: 4 rows (q*4+rr), col c; tanh + 2B sc0sc1 stores
        unsigned h0v, h1v, h2v, h3v;
        if (LAYER == 0) {
            h0v = f2bf(tanhf(acc[0] + bf2f((ushort_t)x0) + bv));
            h1v = f2bf(tanhf(acc[1] + bf2f((ushort_t)x1) + bv));
            h2v = f2bf(tanhf(acc[2] + bf2f((ushort_t)x2) + bv));
            h3v = f2bf(tanhf(acc[3] + bf2f((ushort_t)x3) + bv));
        } else {
            h0v = f2bf(tanhf(acc[0] + bv));
            h1v = f2bf(tanhf(acc[1] + bv));
            h2v = f2bf(tanhf(acc[2] + bv));
            h3v = f2bf(tanhf(acc[3] + bv));
        }
        // dst rows: same addresses as xrow0/xrow2 pattern (xall at time r)
        ushort_t* d0 = xall + (size_t)r * BH + (size_t)(b0 + q * 4) * H_ + c;
        ushort_t* d2 = d0 + 2 * H_;
        asm volatile(
            "global_store_short %0, %2, off sc0 sc1\n\t"
            "global_store_short %0, %3, off offset:2048 sc0 sc1\n\t"
            "global_store_short %1, %4, off sc0 sc1\n\t"
            "global_store_short %1, %5, off offset:2048 sc0 sc1\n\t"
            "s_waitcnt vmcnt(0)"
            :
            : "v"(d0), "v"(d2), "v"(h0v), "v"(h1v), "v"(h2v), "v"(h3v)
            : "memory");

        // ---- publish this wave's flag (stores already drained above)
        if (r < 511 && lane == 0)
            __hip_atomic_store(myflag, r + 1, __ATOMIC_RELAXED, __HIP_MEMORY_SCOPE_SYSTEM);
    }
}

// ---------------------------------------------------------------- launch ----
extern "C" void kernel_launch(void* const* d_in, const int* in_sizes, int n_in,
                              void* d_out, int out_size, void* d_ws, size_t ws_size,
                              hipStream_t stream) {
    (void)in_sizes; (void)n_in; (void)out_size; (void)ws_size;
    const float* emb   = (const float*)d_in[0];
    const float* h0    = (const float*)d_in[1];
    const float* W_ih0 = (const float*)d_in[2];
    const float* b_ih0 = (const float*)d_in[3];
    const float* W_ih1 = (const float*)d_in[4];
    const float* b_ih1 = (const float*)d_in[5];
    const float* W_hh0 = (const float*)d_in[6];
    const float* b_hh0 = (const float*)d_in[7];
    const float* W_hh1 = (const float*)d_in[8];
    const float* b_hh1 = (const float*)d_in[9];
    const float* W_out = (const float*)d_in[10];
    const float* b_out = (const float*)d_in[11];
    float* out = (float*)d_out;

    char* ws = (char*)d_ws;
    int*      bar   = (int*)ws;                      // flags (16384 ints)
    ushort_t* hinit = (ushort_t*)(ws + 131072);      // 2*B*H bf16
    ushort_t* xp    = (ushort_t*)(ws + 131072 + 2 * BH * 2);  // (T,B,H): x0 -> h0
    ushort_t* xq    = xp + (size_t)T_ * BH;                   // (T,B,H): h1

    prep_kernel<<<512, 256, 0, stream>>>(h0, hinit, bar);

    // xp = emb . W_ih0^T + b_ih0   (stored (T,B,H))
    gemm_bt<0><<<dim3(H_ / 128, (B_ * T_) / 128), 256, 0, stream>>>(
        emb, W_ih0, b_ih0, xp, H_, E_);

    // layer 0: xp := h0_all (in place)
    rnn_wave<0><<<64, 256, 0, stream>>>(xp, (const ushort_t*)nullptr, hinit,
                                        W_hh0, W_hh0, b_hh0, b_hh0, bar);

    // layer 1: xq := h1_all; x-term = h0_all . W_ih1^T computed pre-poll
    rnn_wave<1><<<64, 256, 0, stream>>>(xq, xp, hinit + BH,
                                        W_ih1, W_hh1, b_ih1, b_hh1, bar);

    // out = h1_all . W_out^T + b_out   ((B,T,O) fp32)
    gemm_bt<2><<<dim3(O_ / 128, (B_ * T_) / 128), 256, 0, stream>>>(
        xq, W_out, b_out, out, O_, H_);
}

// Round 9
// 3468.421 us; speedup vs baseline: 2.0271x; 2.0271x over previous
//
#include <hip/hip_runtime.h>
#include <cmath>

#define B_ 64
#define T_ 512
#define E_ 512
#define H_ 1024
#define O_ 512
#define BH (B_ * H_)

typedef unsigned short ushort_t;
typedef __bf16 bf16x8 __attribute__((ext_vector_type(8)));
typedef float f32x4 __attribute__((ext_vector_type(4)));

__device__ __forceinline__ ushort_t f2bf(float f) {
    union { float f; unsigned int u; } x; x.f = f;
    unsigned int r = x.u + 0x7fffu + ((x.u >> 16) & 1u);
    return (ushort_t)(r >> 16);
}
__device__ __forceinline__ float bf2f(ushort_t u) {
    union { unsigned int u; float f; } x; x.u = ((unsigned int)u) << 16;
    return x.f;
}
__device__ __forceinline__ uint4 pack8bf(float4 v0, float4 v1) {
    uint4 pk;
    pk.x = (unsigned)f2bf(v0.x) | ((unsigned)f2bf(v0.y) << 16);
    pk.y = (unsigned)f2bf(v0.z) | ((unsigned)f2bf(v0.w) << 16);
    pk.z = (unsigned)f2bf(v1.x) | ((unsigned)f2bf(v1.y) << 16);
    pk.w = (unsigned)f2bf(v1.z) | ((unsigned)f2bf(v1.w) << 16);
    return pk;
}
__device__ __forceinline__ bf16x8 pack8(const float* src) {
    float4 v0 = *(const float4*)src;
    float4 v1 = *(const float4*)(src + 4);
    union { uint4 u; bf16x8 b; } c;
    c.u = pack8bf(v0, v1);
    return c.b;
}
__device__ __forceinline__ bf16x8 asbf(uint4 u) {
    union { uint4 u; bf16x8 b; } c; c.u = u; return c.b;
}

// ---------------------------------------------------------------- prep ------
__global__ void prep_kernel(const float* __restrict__ h0, ushort_t* __restrict__ hinit,
                            int* __restrict__ bar) {
    int i = blockIdx.x * blockDim.x + threadIdx.x;
    if (i < 32768) bar[i] = 0;  // flags: 2 layers x 4 groups x 128 flags x 32-int stride
    if (i < 2 * BH) hinit[i] = f2bf(h0[i]);
}

// ------------------------------------------------ big GEMM: C = A*W^T + b ---
// MODE 0: A fp32 (emb, (B,T,E), row r=t*64+b -> emb row (b,t)), out bf16 direct rows
// MODE 2: A bf16 direct rows, out fp32 remapped row r=t*64+b -> out row (b,t)
template <int MODE>
__launch_bounds__(256)
__global__ void gemm_bt(const void* __restrict__ Ap, const float* __restrict__ Wp,
                        const float* __restrict__ bias, void* __restrict__ outp,
                        int N, int K) {
    __shared__ __align__(16) ushort_t As[128 * 72];
    __shared__ __align__(16) ushort_t Bs[128 * 72];
    const int tid = threadIdx.x;
    const int lane = tid & 63;
    const int w = tid >> 6;
    const int wm = (w >> 1) * 64;
    const int wn = (w & 1) * 64;
    const int q = lane >> 4;
    const int l16 = lane & 15;
    const int m0 = blockIdx.y * 128;
    const int n0 = blockIdx.x * 128;

    const float*    Af = (const float*)Ap;
    const ushort_t* Ab = (const ushort_t*)Ap;

    f32x4 zero = {0.f, 0.f, 0.f, 0.f};
    f32x4 acc[4][4];
#pragma unroll
    for (int i = 0; i < 4; i++)
#pragma unroll
        for (int j = 0; j < 4; j++) acc[i][j] = zero;

    for (int k0 = 0; k0 < K; k0 += 64) {
#pragma unroll
        for (int it = 0; it < 4; it++) {
            int task = tid + it * 256;
            int row = task >> 3, seg = task & 7;
            if (MODE == 0) {
                int Ra = m0 + row;
                const float* src = Af + (size_t)((Ra & 63) * T_ + (Ra >> 6)) * K + k0 + seg * 8;
                float4 v0 = *(const float4*)src;
                float4 v1 = *(const float4*)(src + 4);
                *(uint4*)&As[row * 72 + seg * 8] = pack8bf(v0, v1);
            } else {
                const ushort_t* src = Ab + (size_t)(m0 + row) * K + k0 + seg * 8;
                *(uint4*)&As[row * 72 + seg * 8] = *(const uint4*)src;
            }
            const float* wsrc = Wp + (size_t)(n0 + row) * K + k0 + seg * 8;
            float4 w0 = *(const float4*)wsrc;
            float4 w1 = *(const float4*)(wsrc + 4);
            *(uint4*)&Bs[row * 72 + seg * 8] = pack8bf(w0, w1);
        }
        __syncthreads();
#pragma unroll
        for (int ks = 0; ks < 64; ks += 32) {
            bf16x8 af[4], bfr[4];
#pragma unroll
            for (int i = 0; i < 4; i++)
                af[i] = *(const bf16x8*)&As[(wm + i * 16 + l16) * 72 + ks + q * 8];
#pragma unroll
            for (int j = 0; j < 4; j++)
                bfr[j] = *(const bf16x8*)&Bs[(wn + j * 16 + l16) * 72 + ks + q * 8];
#pragma unroll
            for (int i = 0; i < 4; i++)
#pragma unroll
                for (int j = 0; j < 4; j++)
                    acc[i][j] = __builtin_amdgcn_mfma_f32_16x16x32_bf16(af[i], bfr[j], acc[i][j], 0, 0, 0);
        }
        __syncthreads();
    }

#pragma unroll
    for (int j = 0; j < 4; j++) {
        int C = n0 + wn + j * 16 + l16;
        float bv = bias[C];
#pragma unroll
        for (int i = 0; i < 4; i++) {
#pragma unroll
            for (int r = 0; r < 4; r++) {
                int R = m0 + wm + i * 16 + q * 4 + r;
                float v = acc[i][j][r] + bv;
                if (MODE == 2) {
                    ((float*)outp)[(size_t)((R & 63) * T_ + (R >> 6)) * N + C] = v;
                } else {
                    ((ushort_t*)outp)[(size_t)R * N + C] = f2bf(v);
                }
            }
        }
    }
}

// -------------------- two-pass recurrence, register-direct staging ----------
// 128 blocks x 256 threads per pass. Block (gb, cb): batch rows [16gb,+16),
// cols [32cb,+32). Wave w covers K-slice [256w,+256); cross-wave Rs reduce.
// A-frags loaded DIRECTLY to registers (no LDS staging): lane pattern matches
// MFMA A-layout (row l16, cols kcol + kk*32), one asm batch of 8 x 16B sc0sc1.
// Per-WAVE flags (128/group): wave drains own store (vmcnt0) then publishes.
// Poll covers all 128 -> also guards the Rs WAR across rounds.
// LAYER 0: h[r] = tanh(h[r-1]·Wa^T + x[r] + ba); x-word pre-poll (plain).
// LAYER 1: h[r] = tanh(xsrc[r]·Wa^T + h[r-1]·Wb^T + ba+bb); x-part MFMA'd
//          pre-poll from xsrc (materialized; 2 batches of 4 loads, plain).
template <int LAYER>
__launch_bounds__(256, 1)
__global__ void rnn_pass(ushort_t* __restrict__ xall,
                         const ushort_t* __restrict__ xsrc,
                         const ushort_t* __restrict__ hin,
                         const float* __restrict__ Wa, const float* __restrict__ Wb,
                         const float* __restrict__ ba, const float* __restrict__ bb,
                         int* __restrict__ bar) {
    __shared__ float Rs[4][16][33];

    const int tid = threadIdx.x;
    const int lane = tid & 63;
    const int w = tid >> 6;
    const int q = lane >> 4;
    const int l16 = lane & 15;
    const int gb = blockIdx.x >> 5;   // 4 batch groups x 32 col blocks
    const int cb = blockIdx.x & 31;
    const int b0 = gb * 16;
    const int n0 = cb * 32;
    int* flags = bar + (LAYER * 4 + gb) * 4096;   // 128 flags, 32-int stride
    int* pollp0 = flags + (lane << 5);
    int* pollp1 = flags + ((lane + 64) << 5);
    int* myflag = flags + ((cb * 4 + w) << 5);

    // ---- register B-fragments (loop-invariant weights; 16/matrix/wave)
    bf16x8 wA[16], wB[16];
#pragma unroll
    for (int g = 0; g < 2; g++)
#pragma unroll
        for (int kk = 0; kk < 8; kk++) {
            size_t off = (size_t)(n0 + g * 16 + l16) * H_ + w * 256 + kk * 32 + q * 8;
            wA[g * 8 + kk] = pack8(Wa + off);
            if (LAYER == 1) wB[g * 8 + kk] = pack8(Wb + off);
        }

    const int em = tid >> 4;            // epilogue row (wave w -> rows 4w..4w+3)
    const int en = (tid & 15) * 2;      // epilogue col pair
    float bv0 = ba[n0 + en], bv1 = ba[n0 + en + 1];
    if (LAYER == 1) { bv0 += bb[n0 + en]; bv1 += bb[n0 + en + 1]; }

    const int kcol = w * 256 + q * 8;   // this lane's A-frag base col

    for (int r = 0; r < 512; r++) {
        f32x4 acc0 = {0.f, 0.f, 0.f, 0.f};
        f32x4 acc1 = {0.f, 0.f, 0.f, 0.f};
        unsigned xw = 0;

        // ---- pre-poll work (barrier-independent)
        if (LAYER == 0) {
            const ushort_t* xaddr = xall + (size_t)r * BH + (size_t)(b0 + em) * H_ + n0 + en;
            asm volatile("global_load_dword %0, %1, off\n\ts_waitcnt vmcnt(0)"
                         : "=&v"(xw) : "v"(xaddr) : "memory");
        } else {
            const ushort_t* xb = xsrc + (size_t)r * BH + (size_t)(b0 + l16) * H_ + kcol;
            uint4 f0, f1, f2, f3;
            asm volatile(
                "global_load_dwordx4 %0, %4, off\n\t"
                "global_load_dwordx4 %1, %4, off offset:64\n\t"
                "global_load_dwordx4 %2, %4, off offset:128\n\t"
                "global_load_dwordx4 %3, %4, off offset:192\n\t"
                "s_waitcnt vmcnt(0)"
                : "=&v"(f0), "=&v"(f1), "=&v"(f2), "=&v"(f3)
                : "v"(xb) : "memory");
            acc0 = __builtin_amdgcn_mfma_f32_16x16x32_bf16(asbf(f0), wA[0], acc0, 0, 0, 0);
            acc1 = __builtin_amdgcn_mfma_f32_16x16x32_bf16(asbf(f0), wA[8], acc1, 0, 0, 0);
            acc0 = __builtin_amdgcn_mfma_f32_16x16x32_bf16(asbf(f1), wA[1], acc0, 0, 0, 0);
            acc1 = __builtin_amdgcn_mfma_f32_16x16x32_bf16(asbf(f1), wA[9], acc1, 0, 0, 0);
            acc0 = __builtin_amdgcn_mfma_f32_16x16x32_bf16(asbf(f2), wA[2], acc0, 0, 0, 0);
            acc1 = __builtin_amdgcn_mfma_f32_16x16x32_bf16(asbf(f2), wA[10], acc1, 0, 0, 0);
            acc0 = __builtin_amdgcn_mfma_f32_16x16x32_bf16(asbf(f3), wA[3], acc0, 0, 0, 0);
            acc1 = __builtin_amdgcn_mfma_f32_16x16x32_bf16(asbf(f3), wA[11], acc1, 0, 0, 0);
            asm volatile(
                "global_load_dwordx4 %0, %4, off offset:256\n\t"
                "global_load_dwordx4 %1, %4, off offset:320\n\t"
                "global_load_dwordx4 %2, %4, off offset:384\n\t"
                "global_load_dwordx4 %3, %4, off offset:448\n\t"
                "s_waitcnt vmcnt(0)"
                : "=&v"(f0), "=&v"(f1), "=&v"(f2), "=&v"(f3)
                : "v"(xb) : "memory");
            acc0 = __builtin_amdgcn_mfma_f32_16x16x32_bf16(asbf(f0), wA[4], acc0, 0, 0, 0);
            acc1 = __builtin_amdgcn_mfma_f32_16x16x32_bf16(asbf(f0), wA[12], acc1, 0, 0, 0);
            acc0 = __builtin_amdgcn_mfma_f32_16x16x32_bf16(asbf(f1), wA[5], acc0, 0, 0, 0);
            acc1 = __builtin_amdgcn_mfma_f32_16x16x32_bf16(asbf(f1), wA[13], acc1, 0, 0, 0);
            acc0 = __builtin_amdgcn_mfma_f32_16x16x32_bf16(asbf(f2), wA[6], acc0, 0, 0, 0);
            acc1 = __builtin_amdgcn_mfma_f32_16x16x32_bf16(asbf(f2), wA[14], acc1, 0, 0, 0);
            acc0 = __builtin_amdgcn_mfma_f32_16x16x32_bf16(asbf(f3), wA[7], acc0, 0, 0, 0);
            acc1 = __builtin_amdgcn_mfma_f32_16x16x32_bf16(asbf(f3), wA[15], acc1, 0, 0, 0);
        }

        // ---- wait: all 128 wave-flags of this group >= r
        if (r > 0) {
            while (true) {
                int v0 = __hip_atomic_load(pollp0, __ATOMIC_RELAXED, __HIP_MEMORY_SCOPE_SYSTEM);
                int v1 = __hip_atomic_load(pollp1, __ATOMIC_RELAXED, __HIP_MEMORY_SCOPE_SYSTEM);
                if ((__ballot(v0 >= r) & __ballot(v1 >= r)) == ~0ull) break;
            }
        }

        // ---- h A-frags: direct-to-register, one batch of 8 sc0sc1 loads
        const ushort_t* hb = ((r == 0) ? hin : (xall + (size_t)(r - 1) * BH))
                             + (size_t)(b0 + l16) * H_ + kcol;
        uint4 g0, g1, g2, g3, g4, g5, g6, g7;
        asm volatile(
            "global_load_dwordx4 %0, %8, off sc0 sc1\n\t"
            "global_load_dwordx4 %1, %8, off offset:64 sc0 sc1\n\t"
            "global_load_dwordx4 %2, %8, off offset:128 sc0 sc1\n\t"
            "global_load_dwordx4 %3, %8, off offset:192 sc0 sc1\n\t"
            "global_load_dwordx4 %4, %8, off offset:256 sc0 sc1\n\t"
            "global_load_dwordx4 %5, %8, off offset:320 sc0 sc1\n\t"
            "global_load_dwordx4 %6, %8, off offset:384 sc0 sc1\n\t"
            "global_load_dwordx4 %7, %8, off offset:448 sc0 sc1\n\t"
            "s_waitcnt vmcnt(0)"
            : "=&v"(g0), "=&v"(g1), "=&v"(g2), "=&v"(g3),
              "=&v"(g4), "=&v"(g5), "=&v"(g6), "=&v"(g7)
            : "v"(hb) : "memory");

        const bf16x8* wH = (LAYER == 1) ? wB : wA;
        acc0 = __builtin_amdgcn_mfma_f32_16x16x32_bf16(asbf(g0), wH[0], acc0, 0, 0, 0);
        acc1 = __builtin_amdgcn_mfma_f32_16x16x32_bf16(asbf(g0), wH[8], acc1, 0, 0, 0);
        acc0 = __builtin_amdgcn_mfma_f32_16x16x32_bf16(asbf(g1), wH[1], acc0, 0, 0, 0);
        acc1 = __builtin_amdgcn_mfma_f32_16x16x32_bf16(asbf(g1), wH[9], acc1, 0, 0, 0);
        acc0 = __builtin_amdgcn_mfma_f32_16x16x32_bf16(asbf(g2), wH[2], acc0, 0, 0, 0);
        acc1 = __builtin_amdgcn_mfma_f32_16x16x32_bf16(asbf(g2), wH[10], acc1, 0, 0, 0);
        acc0 = __builtin_amdgcn_mfma_f32_16x16x32_bf16(asbf(g3), wH[3], acc0, 0, 0, 0);
        acc1 = __builtin_amdgcn_mfma_f32_16x16x32_bf16(asbf(g3), wH[11], acc1, 0, 0, 0);
        acc0 = __builtin_amdgcn_mfma_f32_16x16x32_bf16(asbf(g4), wH[4], acc0, 0, 0, 0);
        acc1 = __builtin_amdgcn_mfma_f32_16x16x32_bf16(asbf(g4), wH[12], acc1, 0, 0, 0);
        acc0 = __builtin_amdgcn_mfma_f32_16x16x32_bf16(asbf(g5), wH[5], acc0, 0, 0, 0);
        acc1 = __builtin_amdgcn_mfma_f32_16x16x32_bf16(asbf(g5), wH[13], acc1, 0, 0, 0);
        acc0 = __builtin_amdgcn_mfma_f32_16x16x32_bf16(asbf(g6), wH[6], acc0, 0, 0, 0);
        acc1 = __builtin_amdgcn_mfma_f32_16x16x32_bf16(asbf(g6), wH[14], acc1, 0, 0, 0);
        acc0 = __builtin_amdgcn_mfma_f32_16x16x32_bf16(asbf(g7), wH[7], acc0, 0, 0, 0);
        acc1 = __builtin_amdgcn_mfma_f32_16x16x32_bf16(asbf(g7), wH[15], acc1, 0, 0, 0);

#pragma unroll
        for (int rr = 0; rr < 4; rr++) {
            Rs[w][q * 4 + rr][l16] = acc0[rr];
            Rs[w][q * 4 + rr][16 + l16] = acc1[rr];
        }
        __syncthreads();

        // ---- reduce 4 waves + tanh + coherent packed store + per-wave flag
        {
            float sA = Rs[0][em][en] + Rs[1][em][en] + Rs[2][em][en] + Rs[3][em][en];
            float sB = Rs[0][em][en + 1] + Rs[1][em][en + 1] + Rs[2][em][en + 1] + Rs[3][em][en + 1];
            if (LAYER == 0) {
                sA += bf2f((ushort_t)(xw & 0xffff));
                sB += bf2f((ushort_t)(xw >> 16));
            }
            sA += bv0;
            sB += bv1;
            unsigned pk = (unsigned)f2bf(tanhf(sA)) | ((unsigned)f2bf(tanhf(sB)) << 16);
            ushort_t* dst = xall + (size_t)r * BH + (size_t)(b0 + em) * H_ + n0 + en;
            asm volatile("global_store_dword %0, %1, off sc0 sc1\n\ts_waitcnt vmcnt(0)"
                         :: "v"(dst), "v"(pk) : "memory");
        }
        if (r < 511 && lane == 0)
            __hip_atomic_store(myflag, r + 1, __ATOMIC_RELAXED, __HIP_MEMORY_SCOPE_SYSTEM);
    }
}

// ---------------------------------------------------------------- launch ----
extern "C" void kernel_launch(void* const* d_in, const int* in_sizes, int n_in,
                              void* d_out, int out_size, void* d_ws, size_t ws_size,
                              hipStream_t stream) {
    (void)in_sizes; (void)n_in; (void)out_size; (void)ws_size;
    const float* emb   = (const float*)d_in[0];
    const float* h0    = (const float*)d_in[1];
    const float* W_ih0 = (const float*)d_in[2];
    const float* b_ih0 = (const float*)d_in[3];
    const float* W_ih1 = (const float*)d_in[4];
    const float* b_ih1 = (const float*)d_in[5];
    const float* W_hh0 = (const float*)d_in[6];
    const float* b_hh0 = (const float*)d_in[7];
    const float* W_hh1 = (const float*)d_in[8];
    const float* b_hh1 = (const float*)d_in[9];
    const float* W_out = (const float*)d_in[10];
    const float* b_out = (const float*)d_in[11];
    float* out = (float*)d_out;

    char* ws = (char*)d_ws;
    int*      bar   = (int*)ws;                      // flags (32768 ints = 128KB)
    ushort_t* hinit = (ushort_t*)(ws + 131072);      // 2*B*H bf16
    ushort_t* xp    = (ushort_t*)(ws + 131072 + 2 * BH * 2);  // (T,B,H): x0 -> h0
    ushort_t* xq    = xp + (size_t)T_ * BH;                   // (T,B,H): h1

    prep_kernel<<<512, 256, 0, stream>>>(h0, hinit, bar);

    // xp = emb . W_ih0^T + b_ih0   (stored (T,B,H))
    gemm_bt<0><<<dim3(H_ / 128, (B_ * T_) / 128), 256, 0, stream>>>(
        emb, W_ih0, b_ih0, xp, H_, E_);

    // layer 0: xp := h0_all (in place)
    rnn_pass<0><<<128, 256, 0, stream>>>(xp, (const ushort_t*)nullptr, hinit,
                                         W_hh0, W_hh0, b_hh0, b_hh0, bar);

    // layer 1: xq := h1_all; x-term = h0_all . W_ih1^T computed pre-poll
    rnn_pass<1><<<128, 256, 0, stream>>>(xq, xp, hinit + BH,
                                         W_ih1, W_hh1, b_ih1, b_hh1, bar);

    // out = h1_all . W_out^T + b_out   ((B,T,O) fp32)
    gemm_bt<2><<<dim3(O_ / 128, (B_ * T_) / 128), 256, 0, stream>>>(
        xq, W_out, b_out, out, O_, H_);
}